// Round 3
// baseline (60.756 us; speedup 1.0000x reference)
//
#include <hip/hip_runtime.h>

// QuantumPatchLayer closed form (see R0):
//   RZ phases cancel in |amp|^2; CNOT ring is a basis permutation; independent
//   RY bits give E[(-1)^(xor S)] = prod_{i in S} cos(x_i):
//     Z0 = c1*c2*c3, Z1 = c0*c1, Z2 = c0*c1*c2, Z3 = c0*c1*c2*c3
// Pure streaming map: 8 MiB in -> 8 MiB out. v2b: 4x f32x4 per thread
// (more loads in flight per wave) + nontemporal load/store (write-once /
// read-once stream, skip cache allocate). Native clang vector type used
// because __builtin_nontemporal_* rejects HIP_vector_type structs.

typedef float f32x4 __attribute__((ext_vector_type(4)));

__device__ __forceinline__ f32x4 qpl_map(f32x4 x) {
    float c0 = __cosf(x.x);
    float c1 = __cosf(x.y);
    float c2 = __cosf(x.z);
    float c3 = __cosf(x.w);
    float c12 = c1 * c2;
    f32x4 o;
    o.x = c12 * c3;   // Z0
    o.y = c0 * c1;    // Z1
    o.z = c0 * c12;   // Z2
    o.w = o.z * c3;   // Z3
    return o;
}

__global__ void __launch_bounds__(256) qpl_kernel(const f32x4* __restrict__ in,
                                                  f32x4* __restrict__ out, int n) {
    // 4 coalesced f32x4 per thread at stride = total-threads: all four
    // loads independent and in flight together.
    int tid = blockIdx.x * blockDim.x + threadIdx.x;
    int stride = gridDim.x * blockDim.x;
    int i0 = tid;
    int i1 = tid + stride;
    int i2 = tid + 2 * stride;
    int i3 = tid + 3 * stride;
    bool v0 = i0 < n, v1 = i1 < n, v2 = i2 < n, v3 = i3 < n;
    f32x4 x0 = {}, x1 = {}, x2 = {}, x3 = {};
    if (v0) x0 = __builtin_nontemporal_load(&in[i0]);
    if (v1) x1 = __builtin_nontemporal_load(&in[i1]);
    if (v2) x2 = __builtin_nontemporal_load(&in[i2]);
    if (v3) x3 = __builtin_nontemporal_load(&in[i3]);
    if (v0) __builtin_nontemporal_store(qpl_map(x0), &out[i0]);
    if (v1) __builtin_nontemporal_store(qpl_map(x1), &out[i1]);
    if (v2) __builtin_nontemporal_store(qpl_map(x2), &out[i2]);
    if (v3) __builtin_nontemporal_store(qpl_map(x3), &out[i3]);
}

extern "C" void kernel_launch(void* const* d_in, const int* in_sizes, int n_in,
                              void* d_out, int out_size, void* d_ws, size_t ws_size,
                              hipStream_t stream) {
    const f32x4* patches = (const f32x4*)d_in[0];  // (B,P,4) fp32
    // d_in[1] = rz_params: provably unused (phases cancel in probabilities)
    f32x4* out = (f32x4*)d_out;
    int n = in_sizes[0] / 4;                       // (batch,patch) pairs = 524288
    const int block = 256;
    const int per_thread = 4;
    int threads = (n + per_thread - 1) / per_thread;
    int grid = (threads + block - 1) / block;      // 512 blocks -> 2 wg/CU
    qpl_kernel<<<grid, block, 0, stream>>>(patches, out, n);
}